// Round 9
// baseline (400.876 us; speedup 1.0000x reference)
//
#include <hip/hip_runtime.h>

#define HH 160
#define WW 160

typedef __attribute__((ext_vector_type(8))) short bf16x8;
typedef __attribute__((ext_vector_type(4))) float f32x4;

static __device__ __forceinline__ unsigned short f32_to_bf16_rne(float f) {
    unsigned u = __float_as_uint(f);
    unsigned r = (u + 0x7FFFu + ((u >> 16) & 1u)) >> 16;
    return (unsigned short)r;
}
static __device__ __forceinline__ float bf16_to_f32(unsigned short h) {
    return __uint_as_float(((unsigned)h) << 16);
}

// async global->LDS, 16B per lane. g includes lane*16; lbase is wave-uniform.
static __device__ __forceinline__ void stage16(const char* g, char* lbase, int lane) {
#if __has_builtin(__builtin_amdgcn_global_load_lds)
    __builtin_amdgcn_global_load_lds(
        (const __attribute__((address_space(1))) unsigned int*)g,
        (__attribute__((address_space(3))) unsigned int*)lbase, 16, 0, 0);
#else
    *(f32x4*)(lbase + lane * 16) = *(const f32x4*)g;
#endif
}

// ---------------------------------------------------------------------------
// Prep: pack pw_w[2] into MFMA B-fragment layout (bf16 hi/lo), and precompute
// BN folds into wfolds (after the 294912-B fragment area).
// tile tn = b*9+kk (16 KB); frag = (ct*4 + kh*2 + comp) (1 KB each).
// Element (lane,j): B[k=kh*32+(lane>>4)*8+j][n=ct*16+(lane&15)], W[cp][c]=pw[(c*9+kk)*64+cp]
// ---------------------------------------------------------------------------
__global__ __launch_bounds__(256) void prep_w_kernel(
    const float* __restrict__ pw0, const float* __restrict__ pw1,
    const float* __restrict__ g0,  const float* __restrict__ bb0,
    const float* __restrict__ m0,  const float* __restrict__ v0,
    const float* __restrict__ g1,  const float* __restrict__ bb1,
    const float* __restrict__ m1,  const float* __restrict__ v1,
    const float* __restrict__ ng,  const float* __restrict__ nbb,
    const float* __restrict__ nm,  const float* __restrict__ nv,
    unsigned short* __restrict__ wF, float* __restrict__ wfolds) {
    int idx = blockIdx.x * 256 + threadIdx.x;   // 288*64 = 18432 frags-lanes
    if (idx >= 18432) {
        if (blockIdx.x == 72 && threadIdx.x < 64) {
            int c = threadIdx.x;
            float s0 = g0[c] * rsqrtf(v0[c] + 1e-5f);
            wfolds[c]        = s0;
            wfolds[64 + c]   = bb0[c] - m0[c] * s0;
            float s1 = g1[c] * rsqrtf(v1[c] + 1e-5f);
            wfolds[128 + c]  = s1;
            wfolds[192 + c]  = bb1[c] - m1[c] * s1;
            float sn = ng[c] * rsqrtf(nv[c] + 1e-5f);
            wfolds[256 + c]  = sn;
            wfolds[320 + c]  = nbb[c] - nm[c] * sn;
        }
        return;
    }
    int lane = idx & 63;
    int frag = idx >> 6;
    int comp = frag & 1;
    int kh   = (frag >> 1) & 1;
    int ct   = (frag >> 2) & 3;
    int t    = frag >> 4;             // b*9+kk
    int bb   = t / 9;
    int kk   = t - bb * 9;
    const float* pw = bb ? pw1 : pw0;
    int c = ct * 16 + (lane & 15);
    bf16x8 pack;
    #pragma unroll
    for (int j = 0; j < 8; ++j) {
        int cp = kh * 32 + (lane >> 4) * 8 + j;
        float v = pw[(c * 9 + kk) * 64 + cp];
        unsigned short hb = f32_to_bf16_rne(v);
        if (comp == 0) pack[j] = (short)hb;
        else           pack[j] = (short)f32_to_bf16_rne(v - bf16_to_f32(hb));
    }
    *(bf16x8*)&wF[frag * 512 + lane * 8] = pack;
}

// ---------------------------------------------------------------------------
// Fused kernel. Block = 4 h-rows x 32 w = 128 px, 4 waves; wave owns one row
// (2 M-frags) x all 64 output channels. t in plain bf16 (hi only); W hi+lo
// (2 MFMA products). B tiles double-buffered via global_load_lds, 1 barrier
// per kk. x loaded directly (unaligned f32x4 + edge fallback). LDS 53.8 KB
// -> 3 blocks/CU (12 waves). All register arrays statically indexed.
// ---------------------------------------------------------------------------
__global__ __launch_bounds__(256, 3) void fused_kernel(
    const float* __restrict__ y,   const float* __restrict__ x,
    const float* __restrict__ dw0, const float* __restrict__ dw1,
    const float* __restrict__ pwb0,const float* __restrict__ pwb1,
    const unsigned short* __restrict__ wF, const float* __restrict__ wfolds,
    float* __restrict__ out)
{
    __shared__ unsigned short t_hi[128 * 64];        // 16 KB, XOR-swizzled
    __shared__ __align__(16) char bbuf[2 * 16384];   // 32 KB B double-buffer
    __shared__ float dwl[2 * 576];                   // 4.5 KB
    // total 53760 B -> 3 blocks/CU

    const int tid  = threadIdx.x;
    const int lane = tid & 63;
    const int wid  = tid >> 6;
    const int cl   = lane & 15;
    const int pg   = lane >> 4;

    // bijective XCD swizzle: 800 = 8 * 100
    const int bid0 = blockIdx.x;
    const int bid  = (bid0 & 7) * 100 + (bid0 >> 3);
    const int n    = bid / 200;
    const int rem  = bid - n * 200;
    const int ht   = rem / 5;
    const int wt   = rem - ht * 5;
    const int h    = ht * 4;
    const int w0   = wt * 32;

    const float* ybase = y + (size_t)n * (64 * HH * WW);
    const float* xbase = x + (size_t)n * (64 * HH * WW);
    const char*  wfb8  = (const char*)wF;

    for (int e = tid; e < 1152; e += 256)
        dwl[e] = (e < 576) ? dw0[e] : dw1[e - 576];
    // stage B tile 0 (async; drained by the syncthreads below)
    #pragma unroll
    for (int it = 0; it < 4; ++it)
        stage16(wfb8 + ((wid + it * 4) << 10) + lane * 16,
                bbuf + ((wid + it * 4) << 10), lane);
    __syncthreads();

    float outacc[2][4][4];   // [mt][ct][rr] - static indices only
    #pragma unroll
    for (int mt = 0; mt < 2; ++mt)
        #pragma unroll
        for (int ct = 0; ct < 4; ++ct)
            #pragma unroll
            for (int rr = 0; rr < 4; ++rr) outacc[mt][ct][rr] = 0.f;

    #pragma unroll
    for (int b = 0; b < 2; ++b) {
        const int r = b + 1;
        if (b) __syncthreads();   // all waves done reading t of prev branch

        // ---- depthwise conv + BN + ReLU -> t_hi (bf16, swizzled) ---------
        {
            const int px = tid & 127;
            const int rl = px >> 5, wl = px & 31;
            const int cb = (tid >> 7) * 4;
            #pragma unroll 1
            for (int it = 0; it < 4; ++it) {
                const int chunk = cb + it;           // 0..7
                const int cp0 = chunk * 8;
                bf16x8 h8;
                #pragma unroll
                for (int jc = 0; jc < 8; ++jc) {
                    const int cp = cp0 + jc;
                    float a = 0.f;
                    #pragma unroll
                    for (int i = 0; i < 3; ++i) {
                        const int hr = h + rl + (i - 1) * r;
                        const bool hok = (unsigned)hr < (unsigned)HH;
                        const float* yr = ybase + ((size_t)cp * HH + hr) * WW;
                        #pragma unroll
                        for (int j = 0; j < 3; ++j) {
                            const int wc = w0 + wl + (j - 1) * r;
                            float yv = (hok && (unsigned)wc < (unsigned)WW) ? yr[wc] : 0.f;
                            a = fmaf(yv, dwl[b * 576 + cp * 9 + i * 3 + j], a);
                        }
                    }
                    const float sc = wfolds[b * 128 + cp];
                    const float sh = wfolds[b * 128 + 64 + cp];
                    float tv = fmaxf(fmaf(a, sc, sh), 0.f);
                    h8[jc] = (short)f32_to_bf16_rne(tv);
                }
                const int phys = chunk ^ ((px >> 1) & 7);
                *(bf16x8*)&t_hi[px * 64 + phys * 8] = h8;
            }
        }
        __syncthreads();

        // ---- A fragments: 32 px (2 M-frags), K=64, hi only (16 VGPRs) ----
        bf16x8 afr0[2], afr1[2];   // [kh]
        #pragma unroll
        for (int kh = 0; kh < 2; ++kh) {
            {
                const int px = wid * 32 + cl;
                const int phys = (kh * 4 + pg) ^ ((px >> 1) & 7);
                afr0[kh] = *(const bf16x8*)&t_hi[px * 64 + phys * 8];
            }
            {
                const int px = wid * 32 + 16 + cl;
                const int phys = (kh * 4 + pg) ^ ((px >> 1) & 7);
                afr1[kh] = *(const bf16x8*)&t_hi[px * 64 + phys * 8];
            }
        }

        // ---- kk loop (rolled): 2-phase B dbuf + direct x loads -----------
        const float* pwbg = b ? pwb1 : pwb0;
        const int xrow_base = h + wid;

        #pragma unroll 1
        for (int di = 0; di < 3; ++di) {
            const int xrow = xrow_base + (di - 1) * r;
            const bool rowok = (unsigned)xrow < (unsigned)HH;
            #pragma unroll 1
            for (int dj = 0; dj < 3; ++dj) {
                const int kk = di * 3 + dj;
                const int tn = b * 9 + kk;
                const char* bcur = bbuf + ((tn & 1) << 14);
                char*       bnxt = bbuf + (((tn & 1) ^ 1) << 14);

                // stage next B tile (flows during MFMAs, drained at barrier)
                if (tn < 17) {
                    const char* s = wfb8 + ((size_t)(tn + 1) << 14);
                    #pragma unroll
                    for (int it = 0; it < 4; ++it)
                        stage16(s + ((wid + it * 4) << 10) + lane * 16,
                                bnxt + ((wid + it * 4) << 10), lane);
                }

                const int colb = w0 + pg * 4 + (dj - 1) * r;
                #pragma unroll
                for (int ct = 0; ct < 4; ++ct) {
                    bf16x8 bfr[2][2];   // [kh][comp]
                    #pragma unroll
                    for (int kh = 0; kh < 2; ++kh)
                        #pragma unroll
                        for (int cm = 0; cm < 2; ++cm)
                            bfr[kh][cm] = *(const bf16x8*)(bcur +
                                ((ct * 4 + kh * 2 + cm) << 10) + lane * 16);

                    const int c = ct * 16 + cl;
                    const float bv = pwbg[c * 9 + kk];
                    f32x4 k0 = {bv, bv, bv, bv};
                    f32x4 k1 = k0;
                    // t_hi x (W_hi + W_lo): 2 products per kh
                    #pragma unroll
                    for (int kh = 0; kh < 2; ++kh) {
                        k0 = __builtin_amdgcn_mfma_f32_16x16x32_bf16(
                            afr0[kh], bfr[kh][0], k0, 0, 0, 0);
                        k0 = __builtin_amdgcn_mfma_f32_16x16x32_bf16(
                            afr0[kh], bfr[kh][1], k0, 0, 0, 0);
                        k1 = __builtin_amdgcn_mfma_f32_16x16x32_bf16(
                            afr1[kh], bfr[kh][0], k1, 0, 0, 0);
                        k1 = __builtin_amdgcn_mfma_f32_16x16x32_bf16(
                            afr1[kh], bfr[kh][1], k1, 0, 0, 0);
                    }

                    // x loads (unaligned f32x4 ok; edge fallback elementwise)
                    const float* xrp = xbase + ((size_t)c * HH + xrow) * WW;
                    f32x4 xv0 = {0.f, 0.f, 0.f, 0.f}, xv1 = {0.f, 0.f, 0.f, 0.f};
                    const int col0 = colb, col1 = colb + 16;
                    if (rowok && col0 >= 0 && col0 <= (WW - 4)) {
                        __builtin_memcpy(&xv0, xrp + col0, 16);
                    } else if (rowok) {
                        #pragma unroll
                        for (int rr = 0; rr < 4; ++rr) {
                            const int xc = col0 + rr;
                            if ((unsigned)xc < (unsigned)WW) xv0[rr] = xrp[xc];
                        }
                    }
                    if (rowok && col1 >= 0 && col1 <= (WW - 4)) {
                        __builtin_memcpy(&xv1, xrp + col1, 16);
                    } else if (rowok) {
                        #pragma unroll
                        for (int rr = 0; rr < 4; ++rr) {
                            const int xc = col1 + rr;
                            if ((unsigned)xc < (unsigned)WW) xv1[rr] = xrp[xc];
                        }
                    }
                    #pragma unroll
                    for (int rr = 0; rr < 4; ++rr) {
                        outacc[0][ct][rr] = fmaf(k0[rr], xv0[rr], outacc[0][ct][rr]);
                        outacc[1][ct][rr] = fmaf(k1[rr], xv1[rr], outacc[1][ct][rr]);
                    }
                }
                __syncthreads();   // drains stage; next tile ready, bcur consumed
            }
        }
    }

    // ---- epilogue: final BN + ReLU, coalesced float4 stores --------------
    {
        const int hrow = h + wid;
        #pragma unroll
        for (int mt = 0; mt < 2; ++mt) {
            const int wc0 = w0 + mt * 16 + pg * 4;
            #pragma unroll
            for (int ct = 0; ct < 4; ++ct) {
                const int c = ct * 16 + cl;
                const float sn = wfolds[256 + c], sh = wfolds[320 + c];
                f32x4 o;
                #pragma unroll
                for (int rr = 0; rr < 4; ++rr)
                    o[rr] = fmaxf(fmaf(outacc[mt][ct][rr], sn, sh), 0.f);
                *(f32x4*)&out[(((size_t)n * 64 + c) * HH + hrow) * WW + wc0] = o;
            }
        }
    }
}

extern "C" void kernel_launch(void* const* d_in, const int* in_sizes, int n_in,
                              void* d_out, int out_size, void* d_ws, size_t ws_size,
                              hipStream_t stream) {
    const float* y    = (const float*)d_in[0];
    const float* x    = (const float*)d_in[1];
    const float* dw0  = (const float*)d_in[2];
    const float* g0   = (const float*)d_in[3];
    const float* b0   = (const float*)d_in[4];
    const float* m0   = (const float*)d_in[5];
    const float* v0   = (const float*)d_in[6];
    const float* pw0  = (const float*)d_in[7];
    const float* pwb0 = (const float*)d_in[8];
    const float* dw1  = (const float*)d_in[9];
    const float* g1   = (const float*)d_in[10];
    const float* b1   = (const float*)d_in[11];
    const float* m1   = (const float*)d_in[12];
    const float* v1   = (const float*)d_in[13];
    const float* pw1  = (const float*)d_in[14];
    const float* pwb1 = (const float*)d_in[15];
    const float* ng   = (const float*)d_in[16];
    const float* nb   = (const float*)d_in[17];
    const float* nm   = (const float*)d_in[18];
    const float* nv   = (const float*)d_in[19];

    unsigned short* wF = (unsigned short*)d_ws;       // 294912 B fragments
    float* wfolds = (float*)((char*)d_ws + 294912);   // + 384 floats BN folds

    prep_w_kernel<<<73, 256, 0, stream>>>(pw0, pw1,
                                          g0, b0, m0, v0,
                                          g1, b1, m1, v1,
                                          ng, nb, nm, nv, wF, wfolds);
    fused_kernel<<<800, 256, 0, stream>>>(y, x, dw0, dw1, pwb0, pwb1,
                                          wF, wfolds, (float*)d_out);
}

// Round 12
// 253.059 us; speedup vs baseline: 1.5841x; 1.5841x over previous
//
#include <hip/hip_runtime.h>

#define HH 160
#define WW 160

typedef __attribute__((ext_vector_type(8))) short bf16x8;
typedef __attribute__((ext_vector_type(4))) float f32x4;

static __device__ __forceinline__ unsigned short f32_to_bf16_rne(float f) {
    unsigned u = __float_as_uint(f);
    unsigned r = (u + 0x7FFFu + ((u >> 16) & 1u)) >> 16;
    return (unsigned short)r;
}
static __device__ __forceinline__ float bf16_to_f32(unsigned short h) {
    return __uint_as_float(((unsigned)h) << 16);
}

// async global->LDS, 16B per lane. g includes lane*16; lbase is wave-uniform.
static __device__ __forceinline__ void stage16(const char* g, char* lbase, int lane) {
#if __has_builtin(__builtin_amdgcn_global_load_lds)
    __builtin_amdgcn_global_load_lds(
        (const __attribute__((address_space(1))) unsigned int*)g,
        (__attribute__((address_space(3))) unsigned int*)lbase, 16, 0, 0);
#else
    *(f32x4*)(lbase + lane * 16) = *(const f32x4*)g;
#endif
}

// ---------------------------------------------------------------------------
// Prep: pack pw_w[2] into MFMA B-fragment layout (bf16 hi/lo), and precompute
// BN folds into wfolds (after the 294912-B fragment area).
// tile tn = b*9+kk (16 KB); frag = (ct*4 + kh*2 + comp) (1 KB each).
// Element (lane,j): B[k=kh*32+(lane>>4)*8+j][n=ct*16+(lane&15)], W[cp][c]=pw[(c*9+kk)*64+cp]
// ---------------------------------------------------------------------------
__global__ __launch_bounds__(256) void prep_w_kernel(
    const float* __restrict__ pw0, const float* __restrict__ pw1,
    const float* __restrict__ g0,  const float* __restrict__ bb0,
    const float* __restrict__ m0,  const float* __restrict__ v0,
    const float* __restrict__ g1,  const float* __restrict__ bb1,
    const float* __restrict__ m1,  const float* __restrict__ v1,
    const float* __restrict__ ng,  const float* __restrict__ nbb,
    const float* __restrict__ nm,  const float* __restrict__ nv,
    unsigned short* __restrict__ wF, float* __restrict__ wfolds) {
    int idx = blockIdx.x * 256 + threadIdx.x;   // 288*64 = 18432 frags-lanes
    if (idx >= 18432) {
        if (blockIdx.x == 72 && threadIdx.x < 64) {
            int c = threadIdx.x;
            float s0 = g0[c] * rsqrtf(v0[c] + 1e-5f);
            wfolds[c]        = s0;
            wfolds[64 + c]   = bb0[c] - m0[c] * s0;
            float s1 = g1[c] * rsqrtf(v1[c] + 1e-5f);
            wfolds[128 + c]  = s1;
            wfolds[192 + c]  = bb1[c] - m1[c] * s1;
            float sn = ng[c] * rsqrtf(nv[c] + 1e-5f);
            wfolds[256 + c]  = sn;
            wfolds[320 + c]  = nbb[c] - nm[c] * sn;
        }
        return;
    }
    int lane = idx & 63;
    int frag = idx >> 6;
    int comp = frag & 1;
    int kh   = (frag >> 1) & 1;
    int ct   = (frag >> 2) & 3;
    int t    = frag >> 4;             // b*9+kk
    int bb   = t / 9;
    int kk   = t - bb * 9;
    const float* pw = bb ? pw1 : pw0;
    int c = ct * 16 + (lane & 15);
    bf16x8 pack;
    #pragma unroll
    for (int j = 0; j < 8; ++j) {
        int cp = kh * 32 + (lane >> 4) * 8 + j;
        float v = pw[(c * 9 + kk) * 64 + cp];
        unsigned short hb = f32_to_bf16_rne(v);
        if (comp == 0) pack[j] = (short)hb;
        else           pack[j] = (short)f32_to_bf16_rne(v - bf16_to_f32(hb));
    }
    *(bf16x8*)&wF[frag * 512 + lane * 8] = pack;
}

// ---------------------------------------------------------------------------
// Fused kernel. Block = 4 h-rows x 32 w = 128 px, 4 waves; wave owns one row
// (2 M-frags) x all 64 output channels. t in plain bf16 (hi only); W hi+lo
// (2 MFMA products per kh). B tiles double-buffered via global_load_lds,
// 1 barrier per kk. x loaded directly, issued BEFORE the MFMA cluster.
// LDS 53.8 KB; launch_bounds(256,2) — (256,3) empirically forces VGPR=84 +
// scratch spills (r3/r9); with ~120 VGPR demand the HW can still co-residate
// 3 blocks/CU. All register arrays statically indexed.
// ---------------------------------------------------------------------------
__global__ __launch_bounds__(256, 2) void fused_kernel(
    const float* __restrict__ y,   const float* __restrict__ x,
    const float* __restrict__ dw0, const float* __restrict__ dw1,
    const float* __restrict__ pwb0,const float* __restrict__ pwb1,
    const unsigned short* __restrict__ wF, const float* __restrict__ wfolds,
    float* __restrict__ out)
{
    __shared__ unsigned short t_hi[128 * 64];        // 16 KB, XOR-swizzled
    __shared__ __align__(16) char bbuf[2 * 16384];   // 32 KB B double-buffer
    __shared__ float dwl[2 * 576];                   // 4.5 KB
    // total 53760 B -> 3 blocks/CU possible

    const int tid  = threadIdx.x;
    const int lane = tid & 63;
    const int wid  = tid >> 6;
    const int cl   = lane & 15;
    const int pg   = lane >> 4;

    // bijective XCD swizzle: 800 = 8 * 100
    const int bid0 = blockIdx.x;
    const int bid  = (bid0 & 7) * 100 + (bid0 >> 3);
    const int n    = bid / 200;
    const int rem  = bid - n * 200;
    const int ht   = rem / 5;
    const int wt   = rem - ht * 5;
    const int h    = ht * 4;
    const int w0   = wt * 32;

    const float* ybase = y + (size_t)n * (64 * HH * WW);
    const float* xbase = x + (size_t)n * (64 * HH * WW);
    const char*  wfb8  = (const char*)wF;

    for (int e = tid; e < 1152; e += 256)
        dwl[e] = (e < 576) ? dw0[e] : dw1[e - 576];
    // stage B tile 0 (async; drained by the syncthreads below)
    #pragma unroll
    for (int it = 0; it < 4; ++it)
        stage16(wfb8 + ((wid + it * 4) << 10) + lane * 16,
                bbuf + ((wid + it * 4) << 10), lane);
    __syncthreads();

    float outacc[2][4][4];   // [mt][ct][rr] - static indices only
    #pragma unroll
    for (int mt = 0; mt < 2; ++mt)
        #pragma unroll
        for (int ct = 0; ct < 4; ++ct)
            #pragma unroll
            for (int rr = 0; rr < 4; ++rr) outacc[mt][ct][rr] = 0.f;

    #pragma unroll
    for (int b = 0; b < 2; ++b) {
        const int r = b + 1;
        if (b) __syncthreads();   // all waves done reading t of prev branch

        // ---- depthwise conv + BN + ReLU -> t_hi (bf16, swizzled) ---------
        {
            const int px = tid & 127;
            const int rl = px >> 5, wl = px & 31;
            const int cb = (tid >> 7) * 4;
            #pragma unroll 1
            for (int it = 0; it < 4; ++it) {
                const int chunk = cb + it;           // 0..7
                const int cp0 = chunk * 8;
                bf16x8 h8;
                #pragma unroll
                for (int jc = 0; jc < 8; ++jc) {
                    const int cp = cp0 + jc;
                    float a = 0.f;
                    #pragma unroll
                    for (int i = 0; i < 3; ++i) {
                        const int hr = h + rl + (i - 1) * r;
                        const bool hok = (unsigned)hr < (unsigned)HH;
                        const float* yr = ybase + ((size_t)cp * HH + hr) * WW;
                        #pragma unroll
                        for (int j = 0; j < 3; ++j) {
                            const int wc = w0 + wl + (j - 1) * r;
                            float yv = (hok && (unsigned)wc < (unsigned)WW) ? yr[wc] : 0.f;
                            a = fmaf(yv, dwl[b * 576 + cp * 9 + i * 3 + j], a);
                        }
                    }
                    const float sc = wfolds[b * 128 + cp];
                    const float sh = wfolds[b * 128 + 64 + cp];
                    float tv = fmaxf(fmaf(a, sc, sh), 0.f);
                    h8[jc] = (short)f32_to_bf16_rne(tv);
                }
                const int phys = chunk ^ ((px >> 1) & 7);
                *(bf16x8*)&t_hi[px * 64 + phys * 8] = h8;
            }
        }
        __syncthreads();

        // ---- A fragments: 32 px (2 M-frags), K=64, hi only (16 VGPRs) ----
        bf16x8 afr0[2], afr1[2];   // [kh]
        #pragma unroll
        for (int kh = 0; kh < 2; ++kh) {
            {
                const int px = wid * 32 + cl;
                const int phys = (kh * 4 + pg) ^ ((px >> 1) & 7);
                afr0[kh] = *(const bf16x8*)&t_hi[px * 64 + phys * 8];
            }
            {
                const int px = wid * 32 + 16 + cl;
                const int phys = (kh * 4 + pg) ^ ((px >> 1) & 7);
                afr1[kh] = *(const bf16x8*)&t_hi[px * 64 + phys * 8];
            }
        }

        // ---- kk loop (rolled): 2-phase B dbuf + direct x loads -----------
        const float* pwbg = b ? pwb1 : pwb0;
        const int xrow_base = h + wid;

        #pragma unroll 1
        for (int di = 0; di < 3; ++di) {
            const int xrow = xrow_base + (di - 1) * r;
            const bool rowok = (unsigned)xrow < (unsigned)HH;
            #pragma unroll 1
            for (int dj = 0; dj < 3; ++dj) {
                const int kk = di * 3 + dj;
                const int tn = b * 9 + kk;
                const char* bcur = bbuf + ((tn & 1) << 14);
                char*       bnxt = bbuf + (((tn & 1) ^ 1) << 14);

                // stage next B tile (flows during MFMAs, drained at barrier)
                if (tn < 17) {
                    const char* s = wfb8 + ((size_t)(tn + 1) << 14);
                    #pragma unroll
                    for (int it = 0; it < 4; ++it)
                        stage16(s + ((wid + it * 4) << 10) + lane * 16,
                                bnxt + ((wid + it * 4) << 10), lane);
                }

                const int colb = w0 + pg * 4 + (dj - 1) * r;
                #pragma unroll
                for (int ct = 0; ct < 4; ++ct) {
                    const int c = ct * 16 + cl;
                    // x loads issued FIRST: latency hides under the MFMAs
                    const float* xrp = xbase + ((size_t)c * HH + xrow) * WW;
                    f32x4 xv0 = {0.f, 0.f, 0.f, 0.f}, xv1 = {0.f, 0.f, 0.f, 0.f};
                    const int col0 = colb, col1 = colb + 16;
                    if (rowok && col0 >= 0 && col0 <= (WW - 4)) {
                        __builtin_memcpy(&xv0, xrp + col0, 16);
                    } else if (rowok) {
                        #pragma unroll
                        for (int rr = 0; rr < 4; ++rr) {
                            const int xc = col0 + rr;
                            if ((unsigned)xc < (unsigned)WW) xv0[rr] = xrp[xc];
                        }
                    }
                    if (rowok && col1 >= 0 && col1 <= (WW - 4)) {
                        __builtin_memcpy(&xv1, xrp + col1, 16);
                    } else if (rowok) {
                        #pragma unroll
                        for (int rr = 0; rr < 4; ++rr) {
                            const int xc = col1 + rr;
                            if ((unsigned)xc < (unsigned)WW) xv1[rr] = xrp[xc];
                        }
                    }

                    bf16x8 bfr[2][2];   // [kh][comp]
                    #pragma unroll
                    for (int kh = 0; kh < 2; ++kh)
                        #pragma unroll
                        for (int cm = 0; cm < 2; ++cm)
                            bfr[kh][cm] = *(const bf16x8*)(bcur +
                                ((ct * 4 + kh * 2 + cm) << 10) + lane * 16);

                    const float bv = pwbg[c * 9 + kk];
                    f32x4 k0 = {bv, bv, bv, bv};
                    f32x4 k1 = k0;
                    // t_hi x (W_hi + W_lo): 2 products per kh
                    #pragma unroll
                    for (int kh = 0; kh < 2; ++kh) {
                        k0 = __builtin_amdgcn_mfma_f32_16x16x32_bf16(
                            afr0[kh], bfr[kh][0], k0, 0, 0, 0);
                        k0 = __builtin_amdgcn_mfma_f32_16x16x32_bf16(
                            afr0[kh], bfr[kh][1], k0, 0, 0, 0);
                        k1 = __builtin_amdgcn_mfma_f32_16x16x32_bf16(
                            afr1[kh], bfr[kh][0], k1, 0, 0, 0);
                        k1 = __builtin_amdgcn_mfma_f32_16x16x32_bf16(
                            afr1[kh], bfr[kh][1], k1, 0, 0, 0);
                    }
                    #pragma unroll
                    for (int rr = 0; rr < 4; ++rr) {
                        outacc[0][ct][rr] = fmaf(k0[rr], xv0[rr], outacc[0][ct][rr]);
                        outacc[1][ct][rr] = fmaf(k1[rr], xv1[rr], outacc[1][ct][rr]);
                    }
                }
                __syncthreads();   // drains stage; next tile ready, bcur consumed
            }
        }
    }

    // ---- epilogue: final BN + ReLU, coalesced float4 stores --------------
    {
        const int hrow = h + wid;
        #pragma unroll
        for (int mt = 0; mt < 2; ++mt) {
            const int wc0 = w0 + mt * 16 + pg * 4;
            #pragma unroll
            for (int ct = 0; ct < 4; ++ct) {
                const int c = ct * 16 + cl;
                const float sn = wfolds[256 + c], sh = wfolds[320 + c];
                f32x4 o;
                #pragma unroll
                for (int rr = 0; rr < 4; ++rr)
                    o[rr] = fmaxf(fmaf(outacc[mt][ct][rr], sn, sh), 0.f);
                *(f32x4*)&out[(((size_t)n * 64 + c) * HH + hrow) * WW + wc0] = o;
            }
        }
    }
}

extern "C" void kernel_launch(void* const* d_in, const int* in_sizes, int n_in,
                              void* d_out, int out_size, void* d_ws, size_t ws_size,
                              hipStream_t stream) {
    const float* y    = (const float*)d_in[0];
    const float* x    = (const float*)d_in[1];
    const float* dw0  = (const float*)d_in[2];
    const float* g0   = (const float*)d_in[3];
    const float* b0   = (const float*)d_in[4];
    const float* m0   = (const float*)d_in[5];
    const float* v0   = (const float*)d_in[6];
    const float* pw0  = (const float*)d_in[7];
    const float* pwb0 = (const float*)d_in[8];
    const float* dw1  = (const float*)d_in[9];
    const float* g1   = (const float*)d_in[10];
    const float* b1   = (const float*)d_in[11];
    const float* m1   = (const float*)d_in[12];
    const float* v1   = (const float*)d_in[13];
    const float* pw1  = (const float*)d_in[14];
    const float* pwb1 = (const float*)d_in[15];
    const float* ng   = (const float*)d_in[16];
    const float* nb   = (const float*)d_in[17];
    const float* nm   = (const float*)d_in[18];
    const float* nv   = (const float*)d_in[19];

    unsigned short* wF = (unsigned short*)d_ws;       // 294912 B fragments
    float* wfolds = (float*)((char*)d_ws + 294912);   // + 384 floats BN folds

    prep_w_kernel<<<73, 256, 0, stream>>>(pw0, pw1,
                                          g0, b0, m0, v0,
                                          g1, b1, m1, v1,
                                          ng, nb, nm, nv, wF, wfolds);
    fused_kernel<<<800, 256, 0, stream>>>(y, x, dw0, dw1, pwb0, pwb1,
                                          wF, wfolds, (float*)d_out);
}